// Round 1
// baseline (222.778 us; speedup 1.0000x reference)
//
#include <hip/hip_runtime.h>
#include <hip/hip_bf16.h>
#include <math.h>

// Engram scan. Fast path: prove on-device that every step is a "create"
// (feedback == 0) and write zeros; exact sequential fallback otherwise.
//
// Soundness of the fast path:
//  * With n0==0 and B<=P, the bank only ever holds verbatim copies of earlier
//    padrao rows, and every step has n<P so do_create always fires unless
//    do_reinf does. do_reinf needs cos >= 0.7 vs a SUBSET of {padrao[j], j<t}.
//  * k_tricheck flags if ANY pair (t, j<t) has cos >= 0.5 (conservative
//    superset check, fp32). No flag => no reinforce possible => all creates
//    => feedback identically zero.
//  * flag also set if n0 != 0 (device) or B > P (host) => exact fallback.

#define LIMIAR_SIM 0.7f
#define LIMIAR_NOVO 0.3f
#define LR 0.01f
#define EPSV 1e-8f
#define CHECK_THRESH 0.5f   // conservative vs 0.7 decision threshold

// ---------------- kernel 1: row norms + flag init ----------------
__global__ __launch_bounds__(256) void k_norms(const float* __restrict__ padrao,
                                               int B, int D, float* __restrict__ pn,
                                               unsigned int* __restrict__ flag,
                                               const int* __restrict__ n0p,
                                               int force_flag) {
    __shared__ float red[4];
    int row = blockIdx.x;
    const float* r = padrao + (long long)row * D;
    float s = 0.0f;
    for (int k = threadIdx.x; k < D; k += 256) { float v = r[k]; s += v * v; }
    for (int off = 32; off > 0; off >>= 1) s += __shfl_down(s, off);
    int wid = threadIdx.x >> 6, lane = threadIdx.x & 63;
    if (lane == 0) red[wid] = s;
    __syncthreads();
    if (threadIdx.x == 0) {
        float tot = red[0] + red[1] + red[2] + red[3];
        pn[row] = fmaxf(sqrtf(tot), EPSV);
        if (row == 0) *flag = (force_flag || (*n0p != 0)) ? 1u : 0u;
    }
}

// ------------- kernel 2: strict-lower-tri cosine check (fp32 tiled) -------------
__global__ __launch_bounds__(256) void k_tricheck(const float* __restrict__ padrao,
                                                  const float* __restrict__ pn,
                                                  int B, int D,
                                                  unsigned int* __restrict__ flag) {
    __shared__ float As[64][65];
    __shared__ float Bs[64][65];
    int bid = blockIdx.x;
    // decode lower-triangular tile index (ti >= tj)
    int ti = (int)((sqrtf(8.0f * (float)bid + 1.0f) - 1.0f) * 0.5f);
    while ((ti + 1) * (ti + 2) / 2 <= bid) ++ti;
    while (ti * (ti + 1) / 2 > bid) --ti;
    int tj = bid - ti * (ti + 1) / 2;
    int r0 = ti * 64, c0 = tj * 64;
    int tid = threadIdx.x;
    int ty = tid >> 4, tx = tid & 15;
    float acc[4][4] = {};
    for (int k0 = 0; k0 < D; k0 += 64) {
        for (int s = tid; s < 64 * 64; s += 256) {
            int rr = s >> 6, cc = s & 63;
            int gc = k0 + cc;
            int gr = r0 + rr;
            As[rr][cc] = (gr < B && gc < D) ? padrao[(long long)gr * D + gc] : 0.0f;
            gr = c0 + rr;
            Bs[rr][cc] = (gr < B && gc < D) ? padrao[(long long)gr * D + gc] : 0.0f;
        }
        __syncthreads();
        for (int kk = 0; kk < 64; ++kk) {
            float a[4], b[4];
#pragma unroll
            for (int i = 0; i < 4; ++i) a[i] = As[ty * 4 + i][kk];
#pragma unroll
            for (int j = 0; j < 4; ++j) b[j] = Bs[tx * 4 + j][kk];
#pragma unroll
            for (int i = 0; i < 4; ++i)
#pragma unroll
                for (int j = 0; j < 4; ++j) acc[i][j] += a[i] * b[j];
        }
        __syncthreads();
    }
    unsigned int hit = 0;
    for (int i = 0; i < 4; ++i)
        for (int j = 0; j < 4; ++j) {
            int t = r0 + ty * 4 + i, jj = c0 + tx * 4 + j;
            if (t < B && jj < B && t > jj) {
                if (acc[i][j] >= CHECK_THRESH * pn[t] * pn[jj]) hit = 1;
            }
        }
    if (hit) atomicOr(flag, 1u);
}

// ---------------- kernel 3: zero the output ----------------
__global__ __launch_bounds__(256) void k_zero(float* __restrict__ out, long long n) {
    long long i = (long long)blockIdx.x * blockDim.x + threadIdx.x;
    long long stride = (long long)gridDim.x * blockDim.x;
    for (; i < n; i += stride) out[i] = 0.0f;
}

// ------- kernel 4: exact sequential fallback (runs only if flag set) -------
__global__ __launch_bounds__(1024) void k_fallback(
    const float* __restrict__ padrao, const float* __restrict__ erro,
    const float* __restrict__ protos0, const float* __restrict__ forca0,
    const int* __restrict__ n0p, const float* __restrict__ gainp,
    float* __restrict__ out, const float* __restrict__ pn_arr,
    float* __restrict__ wprotos, float* __restrict__ wforca,
    float* __restrict__ wprotn, const unsigned int* __restrict__ flag,
    int runnable, int B, int D, int P) {
    if (!runnable) return;
    if (*flag == 0) return;
    const int tid = threadIdx.x;
    const int NT = blockDim.x;
    __shared__ float rv[1024];
    __shared__ int ri[1024];
    // init bank state in workspace
    for (long long i = tid; i < (long long)P * D; i += NT) wprotos[i] = protos0[i];
    for (int i = tid; i < P; i += NT) wforca[i] = forca0[i];
    __syncthreads();
    for (int j = tid; j < P; j += NT) {
        const float* r = wprotos + (long long)j * D;
        float s = 0.0f;
        for (int k = 0; k < D; ++k) s += r[k] * r[k];
        wprotn[j] = fmaxf(sqrtf(s), EPSV);
    }
    int n = *n0p;
    float gain = *gainp;
    __syncthreads();
    for (int t = 0; t < B; ++t) {
        const float* p = padrao + (long long)t * D;
        float pn = pn_arr[t];
        // cosine argmax over valid slots (first-index tie-break like jnp.argmax)
        float best = -INFINITY; int bidx = 0;
        for (int j = tid; j < n; j += NT) {
            const float* r = wprotos + (long long)j * D;
            float d = 0.0f;
            for (int k = 0; k < D; ++k) d += r[k] * p[k];
            float sim = d / (wprotn[j] * pn);
            if (sim > best) { best = sim; bidx = j; }
        }
        rv[tid] = best; ri[tid] = bidx;
        __syncthreads();
        for (int off = NT >> 1; off > 0; off >>= 1) {
            if (tid < off) {
                float ov = rv[tid + off]; int oi = ri[tid + off];
                if (ov > rv[tid] || (ov == rv[tid] && oi < ri[tid])) { rv[tid] = ov; ri[tid] = oi; }
            }
            __syncthreads();
        }
        float max_sim = rv[0]; int idx = ri[0];
        __syncthreads();
        float err = erro[t];
        bool is_empty = (n == 0);
        bool do_reinf = (!is_empty) && (max_sim >= LIMIAR_SIM);
        bool do_create = is_empty || ((!do_reinf) && ((err > LIMIAR_NOVO) || (n < P)));
        if (do_create) {
            int cidx = n;
            if (n >= P) {  // overwrite weakest (first-index argmin of forca)
                float bv = INFINITY; int bi = 0;
                for (int j = tid; j < P; j += NT) {
                    float f = wforca[j];
                    if (f < bv) { bv = f; bi = j; }
                }
                rv[tid] = bv; ri[tid] = bi;
                __syncthreads();
                for (int off = NT >> 1; off > 0; off >>= 1) {
                    if (tid < off) {
                        float ov = rv[tid + off]; int oi = ri[tid + off];
                        if (ov < rv[tid] || (ov == rv[tid] && oi < ri[tid])) { rv[tid] = ov; ri[tid] = oi; }
                    }
                    __syncthreads();
                }
                cidx = ri[0];
                __syncthreads();
            }
            float* dst = wprotos + (long long)cidx * D;
            float* o = out + (long long)t * D;
            for (int k = tid; k < D; k += NT) { dst[k] = p[k]; o[k] = 0.0f; }
            if (tid == 0) { wforca[cidx] = 1.0f; wprotn[cidx] = pn; }
            if (n < P) n = n + 1;
        } else if (do_reinf) {
            float* dst = wprotos + (long long)idx * D;
            float fr_new = wforca[idx] + LR;
            float* o = out + (long long)t * D;
            float s2 = 0.0f;
            for (int k = tid; k < D; k += NT) {
                float np_ = (1.0f - LR) * dst[k] + LR * p[k];
                dst[k] = np_;
                o[k] = (np_ - p[k]) * fr_new * gain;
                s2 += np_ * np_;
            }
            rv[tid] = s2;
            __syncthreads();
            for (int off = NT >> 1; off > 0; off >>= 1) {
                if (tid < off) rv[tid] += rv[tid + off];
                __syncthreads();
            }
            if (tid == 0) { wforca[idx] = fr_new; wprotn[idx] = fmaxf(sqrtf(rv[0]), EPSV); }
        } else {
            const float* src = wprotos + (long long)idx * D;
            float fr = wforca[idx];
            float* o = out + (long long)t * D;
            for (int k = tid; k < D; k += NT) o[k] = (src[k] - p[k]) * fr * gain;
        }
        __syncthreads();
    }
}

extern "C" void kernel_launch(void* const* d_in, const int* in_sizes, int n_in,
                              void* d_out, int out_size, void* d_ws, size_t ws_size,
                              hipStream_t stream) {
    const float* padrao  = (const float*)d_in[0];
    const float* erro    = (const float*)d_in[1];
    const float* protos0 = (const float*)d_in[2];
    const float* forca0  = (const float*)d_in[3];
    const int*   n0p     = (const int*)d_in[5];
    const float* gainp   = (const float*)d_in[6];
    const int B = in_sizes[1];
    const int D = (B > 0) ? in_sizes[0] / B : 0;
    const int P = in_sizes[3];

    char* ws = (char*)d_ws;
    unsigned int* flag = (unsigned int*)ws;
    float* pn = (float*)(ws + 64);
    size_t off_protos = ((64 + (size_t)B * 4) + 63) & ~(size_t)63;
    float* wprotos = (float*)(ws + off_protos);
    size_t off_forca = off_protos + (size_t)P * (size_t)D * 4;
    float* wforca = (float*)(ws + off_forca);
    size_t off_protn = off_forca + (size_t)P * 4;
    float* wprotn = (float*)(ws + off_protn);
    size_t need = off_protn + (size_t)P * 4;
    int runnable = (ws_size >= need) ? 1 : 0;   // fallback state fits in ws?
    int force_flag = (B > P) ? 1 : 0;           // bank can fill -> fast path unsound

    k_norms<<<B, 256, 0, stream>>>(padrao, B, D, pn, flag, n0p, force_flag);

    int nT = (B + 63) / 64;
    int nblk = nT * (nT + 1) / 2;
    k_tricheck<<<nblk, 256, 0, stream>>>(padrao, pn, B, D, flag);

    long long outN = (long long)out_size;
    int zb = (int)((outN / 4 + 255) / 256);
    if (zb > 4096) zb = 4096;
    if (zb < 1) zb = 1;
    k_zero<<<zb, 256, 0, stream>>>((float*)d_out, outN);

    k_fallback<<<1, 1024, 0, stream>>>(padrao, erro, protos0, forca0, n0p, gainp,
                                       (float*)d_out, pn, wprotos, wforca, wprotn,
                                       flag, runnable, B, D, P);
}

// Round 4
// 46.977 us; speedup vs baseline: 4.7423x; 4.7423x over previous
//
#include <hip/hip_runtime.h>
#include <hip/hip_bf16.h>
#include <math.h>

// Engram scan. Fast path: prove on-device that every step is a "create"
// (feedback == 0) and write zeros; exact sequential fallback otherwise.
//
// Soundness of the fast path:
//  * With n0==0 and B<=P, the bank only ever holds verbatim copies of earlier
//    padrao rows, and every step has n<P so do_create always fires unless
//    do_reinf does. do_reinf needs cos >= 0.7 vs a SUBSET of {padrao[j], j<t}.
//  * The tri-check flags if ANY pair (t, j<t) has cos >= 0.5 (conservative:
//    bf16 input rounding perturbs cosine by <= ~0.004, margin 0.5 vs 0.7).
//    No flag => no reinforce possible => all creates => feedback == 0.
//  * flag also set if n0 != 0 (device) or B > P (host) => exact fallback.
//  * MFMA layout risk is fail-safe: k-permutation cancels (both operands use
//    the same lane->k map, Gram sums over k); a C-layout transpose only
//    changes which (t,jj) label an entry gets -- worst case a false flag,
//    which routes to the exact fallback (slow but correct).

#define LIMIAR_SIM 0.7f
#define LIMIAR_NOVO 0.3f
#define LR 0.01f
#define EPSV 1e-8f
#define CHECK_THRESH 0.5f   // conservative vs 0.7 decision threshold

typedef __attribute__((ext_vector_type(4))) float f32x4;
typedef __attribute__((ext_vector_type(8))) short bf16x8;

static __device__ inline unsigned short f2bf(float f) {
    unsigned int u = __float_as_uint(f);
    unsigned int r = (u + 0x7FFFu + ((u >> 16) & 1u)) >> 16;
    return (unsigned short)r;
}

// ---------------- kernel 1: row norms + flag init ----------------
__global__ __launch_bounds__(256) void k_norms(const float* __restrict__ padrao,
                                               int B, int D, float* __restrict__ pn,
                                               unsigned int* __restrict__ flag,
                                               const int* __restrict__ n0p,
                                               int force_flag) {
    __shared__ float red[4];
    int row = blockIdx.x;
    const float* r = padrao + (long long)row * D;
    float s = 0.0f;
    if ((D & 3) == 0) {
        for (int k = threadIdx.x * 4; k < D; k += 1024) {
            float4 v = *(const float4*)(r + k);
            s += v.x * v.x + v.y * v.y + v.z * v.z + v.w * v.w;
        }
    } else {
        for (int k = threadIdx.x; k < D; k += 256) { float v = r[k]; s += v * v; }
    }
    for (int off = 32; off > 0; off >>= 1) s += __shfl_down(s, off);
    int wid = threadIdx.x >> 6, lane = threadIdx.x & 63;
    if (lane == 0) red[wid] = s;
    __syncthreads();
    if (threadIdx.x == 0) {
        float tot = red[0] + red[1] + red[2] + red[3];
        pn[row] = fmaxf(sqrtf(tot), EPSV);
        if (row == 0) *flag = (force_flag || (*n0p != 0)) ? 1u : 0u;
    }
}

// ---------------- kernel 1b: fp32 -> bf16 conversion ----------------
__global__ __launch_bounds__(256) void k_tobf16(const float* __restrict__ x,
                                                unsigned short* __restrict__ xb,
                                                long long n4) {
    long long i = (long long)blockIdx.x * 256 + threadIdx.x;
    long long stride = (long long)gridDim.x * 256;
    for (; i < n4; i += stride) {
        float4 v = ((const float4*)x)[i];
        ushort4 o;
        o.x = f2bf(v.x); o.y = f2bf(v.y); o.z = f2bf(v.z); o.w = f2bf(v.w);
        ((ushort4*)xb)[i] = o;
    }
}

// ------------- kernel 2 (MFMA): strict-lower-tri cosine check -------------
// 64x64 output tile per block, 4 waves K-split (each K = D/4), direct global
// bf16 fragment loads (L2/L3-resident), LDS cross-wave reduce, threshold scan.
__global__ __launch_bounds__(256) void k_trimfma(const unsigned short* __restrict__ xb,
                                                 const float* __restrict__ pn,
                                                 int B, int D,
                                                 unsigned int* __restrict__ flag) {
    __shared__ float red[64][65];
    int bid = blockIdx.x;
    int ti = (int)((sqrtf(8.0f * (float)bid + 1.0f) - 1.0f) * 0.5f);
    while ((ti + 1) * (ti + 2) / 2 <= bid) ++ti;
    while (ti * (ti + 1) / 2 > bid) --ti;
    int tj = bid - ti * (ti + 1) / 2;
    int r0 = ti * 64, c0 = tj * 64;
    int tid = threadIdx.x;
    int w = tid >> 6, l = tid & 63;
    int lrow = l & 15;          // row/col within a 16-wide fragment
    int kofs = (l >> 4) * 8;    // k offset within a K=32 step
    f32x4 acc[4][4] = {};
    int kbase = w * (D >> 2);
    int ksteps = D >> 7;        // (D/4) / 32
    for (int ks = 0; ks < ksteps; ++ks) {
        int k0 = kbase + ks * 32 + kofs;
        bf16x8 a[4], b[4];
#pragma unroll
        for (int i = 0; i < 4; ++i)
            a[i] = *(const bf16x8*)(xb + (long long)(r0 + i * 16 + lrow) * D + k0);
#pragma unroll
        for (int j = 0; j < 4; ++j)
            b[j] = *(const bf16x8*)(xb + (long long)(c0 + j * 16 + lrow) * D + k0);
#pragma unroll
        for (int i = 0; i < 4; ++i)
#pragma unroll
            for (int j = 0; j < 4; ++j)
                acc[i][j] = __builtin_amdgcn_mfma_f32_16x16x32_bf16(a[i], b[j], acc[i][j], 0, 0, 0);
    }
    // cross-wave reduction (wave w holds partial sums over its K quarter)
    int crow = (l >> 4) * 4;    // + reg index
    int ccol = l & 15;
    for (int wt = 0; wt < 4; ++wt) {
        if (w == wt) {
#pragma unroll
            for (int i = 0; i < 4; ++i)
#pragma unroll
                for (int j = 0; j < 4; ++j)
#pragma unroll
                    for (int r = 0; r < 4; ++r) {
                        int rr = i * 16 + crow + r, cc = j * 16 + ccol;
                        if (wt == 0) red[rr][cc] = acc[i][j][r];
                        else red[rr][cc] += acc[i][j][r];
                    }
        }
        __syncthreads();
    }
    // threshold scan (strict lower triangle only)
    unsigned int hit = 0;
    for (int s = tid; s < 64 * 64; s += 256) {
        int rr = s >> 6, cc = s & 63;
        int t = r0 + rr, jj = c0 + cc;
        if (t < B && jj < B && t > jj) {
            if (red[rr][cc] >= CHECK_THRESH * pn[t] * pn[jj]) hit = 1;
        }
    }
    if (hit) atomicOr(flag, 1u);
}

// ------------- kernel 2 (fp32 fallback path for ragged shapes) -------------
__global__ __launch_bounds__(256) void k_tricheck(const float* __restrict__ padrao,
                                                  const float* __restrict__ pn,
                                                  int B, int D,
                                                  unsigned int* __restrict__ flag) {
    __shared__ float As[64][65];
    __shared__ float Bs[64][65];
    int bid = blockIdx.x;
    int ti = (int)((sqrtf(8.0f * (float)bid + 1.0f) - 1.0f) * 0.5f);
    while ((ti + 1) * (ti + 2) / 2 <= bid) ++ti;
    while (ti * (ti + 1) / 2 > bid) --ti;
    int tj = bid - ti * (ti + 1) / 2;
    int r0 = ti * 64, c0 = tj * 64;
    int tid = threadIdx.x;
    int ty = tid >> 4, tx = tid & 15;
    float acc[4][4] = {};
    for (int k0 = 0; k0 < D; k0 += 64) {
        for (int s = tid; s < 64 * 64; s += 256) {
            int rr = s >> 6, cc = s & 63;
            int gc = k0 + cc;
            int gr = r0 + rr;
            As[rr][cc] = (gr < B && gc < D) ? padrao[(long long)gr * D + gc] : 0.0f;
            gr = c0 + rr;
            Bs[rr][cc] = (gr < B && gc < D) ? padrao[(long long)gr * D + gc] : 0.0f;
        }
        __syncthreads();
        for (int kk = 0; kk < 64; ++kk) {
            float a[4], b[4];
#pragma unroll
            for (int i = 0; i < 4; ++i) a[i] = As[ty * 4 + i][kk];
#pragma unroll
            for (int j = 0; j < 4; ++j) b[j] = Bs[tx * 4 + j][kk];
#pragma unroll
            for (int i = 0; i < 4; ++i)
#pragma unroll
                for (int j = 0; j < 4; ++j) acc[i][j] += a[i] * b[j];
        }
        __syncthreads();
    }
    unsigned int hit = 0;
    for (int i = 0; i < 4; ++i)
        for (int j = 0; j < 4; ++j) {
            int t = r0 + ty * 4 + i, jj = c0 + tx * 4 + j;
            if (t < B && jj < B && t > jj) {
                if (acc[i][j] >= CHECK_THRESH * pn[t] * pn[jj]) hit = 1;
            }
        }
    if (hit) atomicOr(flag, 1u);
}

// ---------------- kernel 3: zero the output ----------------
__global__ __launch_bounds__(256) void k_zero(float4* __restrict__ out, long long n4) {
    long long i = (long long)blockIdx.x * blockDim.x + threadIdx.x;
    long long stride = (long long)gridDim.x * blockDim.x;
    float4 z = {0.f, 0.f, 0.f, 0.f};
    for (; i < n4; i += stride) out[i] = z;
}
__global__ __launch_bounds__(256) void k_zero_s(float* __restrict__ out, long long n) {
    long long i = (long long)blockIdx.x * blockDim.x + threadIdx.x;
    long long stride = (long long)gridDim.x * blockDim.x;
    for (; i < n; i += stride) out[i] = 0.0f;
}

// ------- kernel 4: exact sequential fallback (runs only if flag set) -------
__global__ __launch_bounds__(1024) void k_fallback(
    const float* __restrict__ padrao, const float* __restrict__ erro,
    const float* __restrict__ protos0, const float* __restrict__ forca0,
    const int* __restrict__ n0p, const float* __restrict__ gainp,
    float* __restrict__ out, const float* __restrict__ pn_arr,
    float* __restrict__ wprotos, float* __restrict__ wforca,
    float* __restrict__ wprotn, const unsigned int* __restrict__ flag,
    int runnable, int B, int D, int P) {
    if (!runnable) return;
    if (*flag == 0) return;
    const int tid = threadIdx.x;
    const int NT = blockDim.x;
    __shared__ float rv[1024];
    __shared__ int ri[1024];
    for (long long i = tid; i < (long long)P * D; i += NT) wprotos[i] = protos0[i];
    for (int i = tid; i < P; i += NT) wforca[i] = forca0[i];
    __syncthreads();
    for (int j = tid; j < P; j += NT) {
        const float* r = wprotos + (long long)j * D;
        float s = 0.0f;
        for (int k = 0; k < D; ++k) s += r[k] * r[k];
        wprotn[j] = fmaxf(sqrtf(s), EPSV);
    }
    int n = *n0p;
    float gain = *gainp;
    __syncthreads();
    for (int t = 0; t < B; ++t) {
        const float* p = padrao + (long long)t * D;
        float pn = pn_arr[t];
        float best = -INFINITY; int bidx = 0;
        for (int j = tid; j < n; j += NT) {
            const float* r = wprotos + (long long)j * D;
            float d = 0.0f;
            for (int k = 0; k < D; ++k) d += r[k] * p[k];
            float sim = d / (wprotn[j] * pn);
            if (sim > best) { best = sim; bidx = j; }
        }
        rv[tid] = best; ri[tid] = bidx;
        __syncthreads();
        for (int off = NT >> 1; off > 0; off >>= 1) {
            if (tid < off) {
                float ov = rv[tid + off]; int oi = ri[tid + off];
                if (ov > rv[tid] || (ov == rv[tid] && oi < ri[tid])) { rv[tid] = ov; ri[tid] = oi; }
            }
            __syncthreads();
        }
        float max_sim = rv[0]; int idx = ri[0];
        __syncthreads();
        float err = erro[t];
        bool is_empty = (n == 0);
        bool do_reinf = (!is_empty) && (max_sim >= LIMIAR_SIM);
        bool do_create = is_empty || ((!do_reinf) && ((err > LIMIAR_NOVO) || (n < P)));
        if (do_create) {
            int cidx = n;
            if (n >= P) {
                float bv = INFINITY; int bi = 0;
                for (int j = tid; j < P; j += NT) {
                    float f = wforca[j];
                    if (f < bv) { bv = f; bi = j; }
                }
                rv[tid] = bv; ri[tid] = bi;
                __syncthreads();
                for (int off = NT >> 1; off > 0; off >>= 1) {
                    if (tid < off) {
                        float ov = rv[tid + off]; int oi = ri[tid + off];
                        if (ov < rv[tid] || (ov == rv[tid] && oi < ri[tid])) { rv[tid] = ov; ri[tid] = oi; }
                    }
                    __syncthreads();
                }
                cidx = ri[0];
                __syncthreads();
            }
            float* dst = wprotos + (long long)cidx * D;
            float* o = out + (long long)t * D;
            for (int k = tid; k < D; k += NT) { dst[k] = p[k]; o[k] = 0.0f; }
            if (tid == 0) { wforca[cidx] = 1.0f; wprotn[cidx] = pn; }
            if (n < P) n = n + 1;
        } else if (do_reinf) {
            float* dst = wprotos + (long long)idx * D;
            float fr_new = wforca[idx] + LR;
            float* o = out + (long long)t * D;
            float s2 = 0.0f;
            for (int k = tid; k < D; k += NT) {
                float np_ = (1.0f - LR) * dst[k] + LR * p[k];
                dst[k] = np_;
                o[k] = (np_ - p[k]) * fr_new * gain;
                s2 += np_ * np_;
            }
            rv[tid] = s2;
            __syncthreads();
            for (int off = NT >> 1; off > 0; off >>= 1) {
                if (tid < off) rv[tid] += rv[tid + off];
                __syncthreads();
            }
            if (tid == 0) { wforca[idx] = fr_new; wprotn[idx] = fmaxf(sqrtf(rv[0]), EPSV); }
        } else {
            const float* src = wprotos + (long long)idx * D;
            float fr = wforca[idx];
            float* o = out + (long long)t * D;
            for (int k = tid; k < D; k += NT) o[k] = (src[k] - p[k]) * fr * gain;
        }
        __syncthreads();
    }
}

extern "C" void kernel_launch(void* const* d_in, const int* in_sizes, int n_in,
                              void* d_out, int out_size, void* d_ws, size_t ws_size,
                              hipStream_t stream) {
    const float* padrao  = (const float*)d_in[0];
    const float* erro    = (const float*)d_in[1];
    const float* protos0 = (const float*)d_in[2];
    const float* forca0  = (const float*)d_in[3];
    const int*   n0p     = (const int*)d_in[5];
    const float* gainp   = (const float*)d_in[6];
    const int B = in_sizes[1];
    const int D = (B > 0) ? in_sizes[0] / B : 0;
    const int P = in_sizes[3];

    char* ws = (char*)d_ws;
    unsigned int* flag = (unsigned int*)ws;
    float* pn = (float*)(ws + 64);
    size_t off_xb = ((64 + (size_t)B * 4) + 63) & ~(size_t)63;
    unsigned short* xb = (unsigned short*)(ws + off_xb);
    size_t off_protos = (off_xb + (size_t)B * (size_t)D * 2 + 63) & ~(size_t)63;
    float* wprotos = (float*)(ws + off_protos);
    size_t off_forca = off_protos + (size_t)P * (size_t)D * 4;
    float* wforca = (float*)(ws + off_forca);
    size_t off_protn = off_forca + (size_t)P * 4;
    float* wprotn = (float*)(ws + off_protn);
    size_t need_total = off_protn + (size_t)P * 4;
    size_t need_fast = off_xb + (size_t)B * (size_t)D * 2;

    int runnable = (ws_size >= need_total) ? 1 : 0;
    int force_flag = (B > P) ? 1 : 0;
    int use_mfma = ((B % 64) == 0) && ((D % 128) == 0) && (ws_size >= need_fast);

    k_norms<<<B, 256, 0, stream>>>(padrao, B, D, pn, flag, n0p, force_flag);

    int nT = (B + 63) / 64;
    int nblk = nT * (nT + 1) / 2;
    if (use_mfma) {
        long long n4 = (long long)B * D / 4;
        int cb = (int)((n4 + 255) / 256); if (cb > 2048) cb = 2048; if (cb < 1) cb = 1;
        k_tobf16<<<cb, 256, 0, stream>>>(padrao, xb, n4);
        k_trimfma<<<nblk, 256, 0, stream>>>(xb, pn, B, D, flag);
    } else {
        k_tricheck<<<nblk, 256, 0, stream>>>(padrao, pn, B, D, flag);
    }

    long long outN = (long long)out_size;
    if ((outN & 3) == 0) {
        long long n4 = outN >> 2;
        int zb = (int)((n4 + 255) / 256); if (zb > 2048) zb = 2048; if (zb < 1) zb = 1;
        k_zero<<<zb, 256, 0, stream>>>((float4*)d_out, n4);
    } else {
        int zb = (int)((outN + 255) / 256); if (zb > 2048) zb = 2048; if (zb < 1) zb = 1;
        k_zero_s<<<zb, 256, 0, stream>>>((float*)d_out, outN);
    }

    k_fallback<<<1, 1024, 0, stream>>>(padrao, erro, protos0, forca0, n0p, gainp,
                                       (float*)d_out, pn, wprotos, wforca, wprotn,
                                       flag, runnable, B, D, P);
}

// Round 5
// 42.123 us; speedup vs baseline: 5.2887x; 1.1152x over previous
//
#include <hip/hip_runtime.h>
#include <hip/hip_bf16.h>
#include <math.h>

// Engram scan. Fast path: prove on-device that every step is a "create"
// (feedback == 0) and write zeros; exact sequential fallback otherwise.
//
// Soundness (unchanged from r1): n0==0 & B<=P => bank holds verbatim copies
// of earlier padrao rows and n<P always => every step creates unless a
// cos>=0.7 match exists among pairs (t, j<t). We flag at cos>=0.5 in bf16
// (rounding perturbs cosine <= ~0.004) -- conservative superset. Flag also
// set if n0!=0 or B>P. MFMA layout errors are fail-safe (worst case: false
// flag -> exact fallback).
//
// r5 structure: 3 dispatches (was 5).
//  k_prep    : row norms + fp32->bf16 convert (one read pass) + flag init
//  k_trimain : output zero-fill (overlapped) + strict-lower-tri MFMA check,
//              parallel 4-region LDS reduce (1 barrier, was 4-phase serial)
//  k_fallback: exact sequential scan, early-exits when flag==0

#define LIMIAR_SIM 0.7f
#define LIMIAR_NOVO 0.3f
#define LR 0.01f
#define EPSV 1e-8f
#define CHECK_THRESH 0.5f   // conservative vs 0.7 decision threshold

typedef __attribute__((ext_vector_type(4))) float f32x4;
typedef __attribute__((ext_vector_type(8))) short bf16x8;

static __device__ inline unsigned short f2bf(float f) {
    unsigned int u = __float_as_uint(f);
    unsigned int r = (u + 0x7FFFu + ((u >> 16) & 1u)) >> 16;
    return (unsigned short)r;
}

// ------- kernel 1: row norms + bf16 convert (fused single read pass) -------
__global__ __launch_bounds__(256) void k_prep(const float* __restrict__ padrao,
                                              int B, int D, float* __restrict__ pn,
                                              unsigned short* __restrict__ xb,
                                              int do_conv,
                                              unsigned int* __restrict__ flag,
                                              const int* __restrict__ n0p,
                                              int force_flag) {
    __shared__ float red[4];
    int row = blockIdx.x;
    const float* r = padrao + (long long)row * D;
    float s = 0.0f;
    if ((D & 3) == 0) {
        for (int k = threadIdx.x * 4; k < D; k += 1024) {
            float4 v = *(const float4*)(r + k);
            s += v.x * v.x + v.y * v.y + v.z * v.z + v.w * v.w;
            if (do_conv) {
                ushort4 o;
                o.x = f2bf(v.x); o.y = f2bf(v.y); o.z = f2bf(v.z); o.w = f2bf(v.w);
                *(ushort4*)(xb + (long long)row * D + k) = o;
            }
        }
    } else {
        for (int k = threadIdx.x; k < D; k += 256) { float v = r[k]; s += v * v; }
    }
    for (int off = 32; off > 0; off >>= 1) s += __shfl_down(s, off);
    int wid = threadIdx.x >> 6, lane = threadIdx.x & 63;
    if (lane == 0) red[wid] = s;
    __syncthreads();
    if (threadIdx.x == 0) {
        float tot = red[0] + red[1] + red[2] + red[3];
        pn[row] = fmaxf(sqrtf(tot), EPSV);
        if (row == 0) *flag = (force_flag || (*n0p != 0)) ? 1u : 0u;
    }
}

// ------- kernel 2: zero-fill (overlapped) + MFMA tri-check, parallel reduce -------
// 64x64 tile/block, 4 waves K-split (K = D/4 each), direct global bf16
// fragment loads (matrix is L2-resident: 4 MB bf16), 4-region LDS reduce.
__global__ __launch_bounds__(256) void k_trimain(const unsigned short* __restrict__ xb,
                                                 const float* __restrict__ pn,
                                                 int B, int D,
                                                 unsigned int* __restrict__ flag,
                                                 float4* __restrict__ out4,
                                                 long long n4, int nblk) {
    __shared__ float red[4][64][65];   // 66.5 KB; +1 pad => 2-way banks (free)
    int bid = blockIdx.x;
    int tid = threadIdx.x;
    // ---- overlapped output zero-fill (fire-and-forget stores) ----
    {
        long long chunk = (n4 + nblk - 1) / nblk;
        long long zb = (long long)bid * chunk;
        long long ze = zb + chunk; if (ze > n4) ze = n4;
        float4 z = {0.f, 0.f, 0.f, 0.f};
        for (long long i = zb + tid; i < ze; i += 256) out4[i] = z;
    }
    // ---- decode lower-triangular tile (ti >= tj) ----
    int ti = (int)((sqrtf(8.0f * (float)bid + 1.0f) - 1.0f) * 0.5f);
    while ((ti + 1) * (ti + 2) / 2 <= bid) ++ti;
    while (ti * (ti + 1) / 2 > bid) --ti;
    int tj = bid - ti * (ti + 1) / 2;
    int r0 = ti * 64, c0 = tj * 64;
    int w = tid >> 6, l = tid & 63;
    int lrow = l & 15;          // row/col within a 16-wide fragment
    int kofs = (l >> 4) * 8;    // k offset within a K=32 step
    f32x4 acc[4][4] = {};
    int kbase = w * (D >> 2);
    int ksteps = D >> 7;        // (D/4) / 32
    for (int ks = 0; ks < ksteps; ++ks) {
        int k0 = kbase + ks * 32 + kofs;
        bf16x8 a[4], b[4];
#pragma unroll
        for (int i = 0; i < 4; ++i)
            a[i] = *(const bf16x8*)(xb + (long long)(r0 + i * 16 + lrow) * D + k0);
#pragma unroll
        for (int j = 0; j < 4; ++j)
            b[j] = *(const bf16x8*)(xb + (long long)(c0 + j * 16 + lrow) * D + k0);
#pragma unroll
        for (int i = 0; i < 4; ++i)
#pragma unroll
            for (int j = 0; j < 4; ++j)
                acc[i][j] = __builtin_amdgcn_mfma_f32_16x16x32_bf16(a[i], b[j], acc[i][j], 0, 0, 0);
    }
    // ---- parallel cross-wave reduction: each wave writes its own region ----
    int crow = (l >> 4) * 4;
    int ccol = l & 15;
#pragma unroll
    for (int i = 0; i < 4; ++i)
#pragma unroll
        for (int j = 0; j < 4; ++j)
#pragma unroll
            for (int r = 0; r < 4; ++r)
                red[w][i * 16 + crow + r][j * 16 + ccol] = acc[i][j][r];
    __syncthreads();
    // ---- threshold scan (strict lower triangle only) ----
    unsigned int hit = 0;
    for (int s = tid; s < 64 * 64; s += 256) {
        int rr = s >> 6, cc = s & 63;
        int t = r0 + rr, jj = c0 + cc;
        if (t < B && jj < B && t > jj) {
            float v = red[0][rr][cc] + red[1][rr][cc] + red[2][rr][cc] + red[3][rr][cc];
            if (v >= CHECK_THRESH * pn[t] * pn[jj]) hit = 1;
        }
    }
    if (hit) atomicOr(flag, 1u);
}

// ------------- fp32 tri-check (ragged-shape fallback path) -------------
__global__ __launch_bounds__(256) void k_tricheck(const float* __restrict__ padrao,
                                                  const float* __restrict__ pn,
                                                  int B, int D,
                                                  unsigned int* __restrict__ flag) {
    __shared__ float As[64][65];
    __shared__ float Bs[64][65];
    int bid = blockIdx.x;
    int ti = (int)((sqrtf(8.0f * (float)bid + 1.0f) - 1.0f) * 0.5f);
    while ((ti + 1) * (ti + 2) / 2 <= bid) ++ti;
    while (ti * (ti + 1) / 2 > bid) --ti;
    int tj = bid - ti * (ti + 1) / 2;
    int r0 = ti * 64, c0 = tj * 64;
    int tid = threadIdx.x;
    int ty = tid >> 4, tx = tid & 15;
    float acc[4][4] = {};
    for (int k0 = 0; k0 < D; k0 += 64) {
        for (int s = tid; s < 64 * 64; s += 256) {
            int rr = s >> 6, cc = s & 63;
            int gc = k0 + cc;
            int gr = r0 + rr;
            As[rr][cc] = (gr < B && gc < D) ? padrao[(long long)gr * D + gc] : 0.0f;
            gr = c0 + rr;
            Bs[rr][cc] = (gr < B && gc < D) ? padrao[(long long)gr * D + gc] : 0.0f;
        }
        __syncthreads();
        for (int kk = 0; kk < 64; ++kk) {
            float a[4], b[4];
#pragma unroll
            for (int i = 0; i < 4; ++i) a[i] = As[ty * 4 + i][kk];
#pragma unroll
            for (int j = 0; j < 4; ++j) b[j] = Bs[tx * 4 + j][kk];
#pragma unroll
            for (int i = 0; i < 4; ++i)
#pragma unroll
                for (int j = 0; j < 4; ++j) acc[i][j] += a[i] * b[j];
        }
        __syncthreads();
    }
    unsigned int hit = 0;
    for (int i = 0; i < 4; ++i)
        for (int j = 0; j < 4; ++j) {
            int t = r0 + ty * 4 + i, jj = c0 + tx * 4 + j;
            if (t < B && jj < B && t > jj) {
                if (acc[i][j] >= CHECK_THRESH * pn[t] * pn[jj]) hit = 1;
            }
        }
    if (hit) atomicOr(flag, 1u);
}

// ---------------- zero kernels (ragged path only) ----------------
__global__ __launch_bounds__(256) void k_zero(float4* __restrict__ out, long long n4) {
    long long i = (long long)blockIdx.x * blockDim.x + threadIdx.x;
    long long stride = (long long)gridDim.x * blockDim.x;
    float4 z = {0.f, 0.f, 0.f, 0.f};
    for (; i < n4; i += stride) out[i] = z;
}
__global__ __launch_bounds__(256) void k_zero_s(float* __restrict__ out, long long n) {
    long long i = (long long)blockIdx.x * blockDim.x + threadIdx.x;
    long long stride = (long long)gridDim.x * blockDim.x;
    for (; i < n; i += stride) out[i] = 0.0f;
}

// ------- kernel 3: exact sequential fallback (runs only if flag set) -------
__global__ __launch_bounds__(1024) void k_fallback(
    const float* __restrict__ padrao, const float* __restrict__ erro,
    const float* __restrict__ protos0, const float* __restrict__ forca0,
    const int* __restrict__ n0p, const float* __restrict__ gainp,
    float* __restrict__ out, const float* __restrict__ pn_arr,
    float* __restrict__ wprotos, float* __restrict__ wforca,
    float* __restrict__ wprotn, const unsigned int* __restrict__ flag,
    int runnable, int B, int D, int P) {
    if (!runnable) return;
    if (*flag == 0) return;
    const int tid = threadIdx.x;
    const int NT = blockDim.x;
    __shared__ float rv[1024];
    __shared__ int ri[1024];
    for (long long i = tid; i < (long long)P * D; i += NT) wprotos[i] = protos0[i];
    for (int i = tid; i < P; i += NT) wforca[i] = forca0[i];
    __syncthreads();
    for (int j = tid; j < P; j += NT) {
        const float* r = wprotos + (long long)j * D;
        float s = 0.0f;
        for (int k = 0; k < D; ++k) s += r[k] * r[k];
        wprotn[j] = fmaxf(sqrtf(s), EPSV);
    }
    int n = *n0p;
    float gain = *gainp;
    __syncthreads();
    for (int t = 0; t < B; ++t) {
        const float* p = padrao + (long long)t * D;
        float pn = pn_arr[t];
        float best = -INFINITY; int bidx = 0;
        for (int j = tid; j < n; j += NT) {
            const float* r = wprotos + (long long)j * D;
            float d = 0.0f;
            for (int k = 0; k < D; ++k) d += r[k] * p[k];
            float sim = d / (wprotn[j] * pn);
            if (sim > best) { best = sim; bidx = j; }
        }
        rv[tid] = best; ri[tid] = bidx;
        __syncthreads();
        for (int off = NT >> 1; off > 0; off >>= 1) {
            if (tid < off) {
                float ov = rv[tid + off]; int oi = ri[tid + off];
                if (ov > rv[tid] || (ov == rv[tid] && oi < ri[tid])) { rv[tid] = ov; ri[tid] = oi; }
            }
            __syncthreads();
        }
        float max_sim = rv[0]; int idx = ri[0];
        __syncthreads();
        float err = erro[t];
        bool is_empty = (n == 0);
        bool do_reinf = (!is_empty) && (max_sim >= LIMIAR_SIM);
        bool do_create = is_empty || ((!do_reinf) && ((err > LIMIAR_NOVO) || (n < P)));
        if (do_create) {
            int cidx = n;
            if (n >= P) {
                float bv = INFINITY; int bi = 0;
                for (int j = tid; j < P; j += NT) {
                    float f = wforca[j];
                    if (f < bv) { bv = f; bi = j; }
                }
                rv[tid] = bv; ri[tid] = bi;
                __syncthreads();
                for (int off = NT >> 1; off > 0; off >>= 1) {
                    if (tid < off) {
                        float ov = rv[tid + off]; int oi = ri[tid + off];
                        if (ov < rv[tid] || (ov == rv[tid] && oi < ri[tid])) { rv[tid] = ov; ri[tid] = oi; }
                    }
                    __syncthreads();
                }
                cidx = ri[0];
                __syncthreads();
            }
            float* dst = wprotos + (long long)cidx * D;
            float* o = out + (long long)t * D;
            for (int k = tid; k < D; k += NT) { dst[k] = p[k]; o[k] = 0.0f; }
            if (tid == 0) { wforca[cidx] = 1.0f; wprotn[cidx] = pn; }
            if (n < P) n = n + 1;
        } else if (do_reinf) {
            float* dst = wprotos + (long long)idx * D;
            float fr_new = wforca[idx] + LR;
            float* o = out + (long long)t * D;
            float s2 = 0.0f;
            for (int k = tid; k < D; k += NT) {
                float np_ = (1.0f - LR) * dst[k] + LR * p[k];
                dst[k] = np_;
                o[k] = (np_ - p[k]) * fr_new * gain;
                s2 += np_ * np_;
            }
            rv[tid] = s2;
            __syncthreads();
            for (int off = NT >> 1; off > 0; off >>= 1) {
                if (tid < off) rv[tid] += rv[tid + off];
                __syncthreads();
            }
            if (tid == 0) { wforca[idx] = fr_new; wprotn[idx] = fmaxf(sqrtf(rv[0]), EPSV); }
        } else {
            const float* src = wprotos + (long long)idx * D;
            float fr = wforca[idx];
            float* o = out + (long long)t * D;
            for (int k = tid; k < D; k += NT) o[k] = (src[k] - p[k]) * fr * gain;
        }
        __syncthreads();
    }
}

extern "C" void kernel_launch(void* const* d_in, const int* in_sizes, int n_in,
                              void* d_out, int out_size, void* d_ws, size_t ws_size,
                              hipStream_t stream) {
    const float* padrao  = (const float*)d_in[0];
    const float* erro    = (const float*)d_in[1];
    const float* protos0 = (const float*)d_in[2];
    const float* forca0  = (const float*)d_in[3];
    const int*   n0p     = (const int*)d_in[5];
    const float* gainp   = (const float*)d_in[6];
    const int B = in_sizes[1];
    const int D = (B > 0) ? in_sizes[0] / B : 0;
    const int P = in_sizes[3];

    char* ws = (char*)d_ws;
    unsigned int* flag = (unsigned int*)ws;
    float* pn = (float*)(ws + 64);
    size_t off_xb = ((64 + (size_t)B * 4) + 63) & ~(size_t)63;
    unsigned short* xb = (unsigned short*)(ws + off_xb);
    size_t off_protos = (off_xb + (size_t)B * (size_t)D * 2 + 63) & ~(size_t)63;
    float* wprotos = (float*)(ws + off_protos);
    size_t off_forca = off_protos + (size_t)P * (size_t)D * 4;
    float* wforca = (float*)(ws + off_forca);
    size_t off_protn = off_forca + (size_t)P * 4;
    float* wprotn = (float*)(ws + off_protn);
    size_t need_total = off_protn + (size_t)P * 4;
    size_t need_fast = off_xb + (size_t)B * (size_t)D * 2;

    int runnable = (ws_size >= need_total) ? 1 : 0;
    int force_flag = (B > P) ? 1 : 0;
    int use_mfma = ((B % 64) == 0) && ((D % 128) == 0) && (ws_size >= need_fast)
                   && ((long long)out_size == (long long)B * D);

    int nT = (B + 63) / 64;
    int nblk = nT * (nT + 1) / 2;
    long long outN = (long long)out_size;

    if (use_mfma) {
        k_prep<<<B, 256, 0, stream>>>(padrao, B, D, pn, xb, 1, flag, n0p, force_flag);
        long long n4 = outN >> 2;   // outN = B*D, D%128==0 => divisible by 4
        k_trimain<<<nblk, 256, 0, stream>>>(xb, pn, B, D, flag, (float4*)d_out, n4, nblk);
    } else {
        k_prep<<<B, 256, 0, stream>>>(padrao, B, D, pn, xb, 0, flag, n0p, force_flag);
        k_tricheck<<<nblk, 256, 0, stream>>>(padrao, pn, B, D, flag);
        if ((outN & 3) == 0) {
            long long n4 = outN >> 2;
            int zb = (int)((n4 + 255) / 256); if (zb > 2048) zb = 2048; if (zb < 1) zb = 1;
            k_zero<<<zb, 256, 0, stream>>>((float4*)d_out, n4);
        } else {
            int zb = (int)((outN + 255) / 256); if (zb > 2048) zb = 2048; if (zb < 1) zb = 1;
            k_zero_s<<<zb, 256, 0, stream>>>((float*)d_out, outN);
        }
    }

    k_fallback<<<1, 1024, 0, stream>>>(padrao, erro, protos0, forca0, n0p, gainp,
                                       (float*)d_out, pn, wprotos, wforca, wprotn,
                                       flag, runnable, B, D, P);
}

// Round 6
// 32.044 us; speedup vs baseline: 6.9522x; 1.3145x over previous
//
#include <hip/hip_runtime.h>
#include <hip/hip_bf16.h>
#include <math.h>

// Engram scan. Fast path: prove on-device that every step is a "create"
// (feedback == 0) and write zeros; exact sequential fallback otherwise.
//
// Soundness (unchanged): n0==0 & B<=P => bank holds verbatim copies of
// earlier padrao rows and n<P always => every step creates unless a
// cos>=0.7 match exists among pairs (t, j<t). We flag at cos>=0.5 in bf16
// (rounding perturbs cosine <= ~0.004) -- conservative superset. Flag also
// set if n0!=0 or B>P. MFMA layout errors are fail-safe (worst case: false
// flag -> exact fallback). k-permutation within lanes cancels (A and B use
// the identical lane->k map; Gram sums over k).
//
// r6 change: fragment-PACKED bf16 layout. k_prep writes
//   xbp[row/16][k/8][row%16][k%8]
// so each MFMA fragment load (16 rows x 8 k per lane-group) is a fully
// contiguous 1KB wave-load -- replaces the previous 16-segment scatter
// (16 rows x 64B at 2KB stride) that left k_trimain latency-bound (~39us,
// ~110 TF effective). Data per lane is bit-identical to the unpacked path.

#define LIMIAR_SIM 0.7f
#define LIMIAR_NOVO 0.3f
#define LR 0.01f
#define EPSV 1e-8f
#define CHECK_THRESH 0.5f   // conservative vs 0.7 decision threshold

typedef __attribute__((ext_vector_type(4))) float f32x4;
typedef __attribute__((ext_vector_type(8))) short bf16x8;

static __device__ inline unsigned short f2bf(float f) {
    unsigned int u = __float_as_uint(f);
    unsigned int r = (u + 0x7FFFu + ((u >> 16) & 1u)) >> 16;
    return (unsigned short)r;
}

// ------- kernel 1: row norms + packed bf16 convert (single read pass) -------
__global__ __launch_bounds__(256) void k_prep(const float* __restrict__ padrao,
                                              int B, int D, float* __restrict__ pn,
                                              unsigned short* __restrict__ xb,
                                              int do_conv,
                                              unsigned int* __restrict__ flag,
                                              const int* __restrict__ n0p,
                                              int force_flag) {
    __shared__ float red[4];
    int row = blockIdx.x;
    const float* r = padrao + (long long)row * D;
    float s = 0.0f;
    if ((D & 3) == 0) {
        for (int k = threadIdx.x * 4; k < D; k += 1024) {
            float4 v = *(const float4*)(r + k);
            s += v.x * v.x + v.y * v.y + v.z * v.z + v.w * v.w;
            if (do_conv) {
                // packed layout: elem = ((row/16 * D/8 + k/8)*16 + row%16)*8 + k%8
                long long uoff = ((((long long)(row >> 4)) * (D >> 3) + (k >> 3)) * 16
                                  + (row & 15)) * 8 + (k & 7);
                ushort4 o;
                o.x = f2bf(v.x); o.y = f2bf(v.y); o.z = f2bf(v.z); o.w = f2bf(v.w);
                *(ushort4*)(xb + uoff) = o;
            }
        }
    } else {
        for (int k = threadIdx.x; k < D; k += 256) { float v = r[k]; s += v * v; }
    }
    for (int off = 32; off > 0; off >>= 1) s += __shfl_down(s, off);
    int wid = threadIdx.x >> 6, lane = threadIdx.x & 63;
    if (lane == 0) red[wid] = s;
    __syncthreads();
    if (threadIdx.x == 0) {
        float tot = red[0] + red[1] + red[2] + red[3];
        pn[row] = fmaxf(sqrtf(tot), EPSV);
        if (row == 0) *flag = (force_flag || (*n0p != 0)) ? 1u : 0u;
    }
}

// ------- kernel 2: zero-fill (overlapped) + MFMA tri-check, packed loads -------
// 64x64 tile/block, 4 waves K-split (K = D/4 each), contiguous 1KB fragment
// loads from the packed L2-resident buffer, 4-region LDS reduce, scan.
__global__ __launch_bounds__(256) void k_trimain(const unsigned short* __restrict__ xb,
                                                 const float* __restrict__ pn,
                                                 int B, int D,
                                                 unsigned int* __restrict__ flag,
                                                 float4* __restrict__ out4,
                                                 long long n4, int nblk) {
    __shared__ float red[4][64][65];   // 66.5 KB; +1 pad => <=2-way banks (free)
    int bid = blockIdx.x;
    int tid = threadIdx.x;
    // ---- overlapped output zero-fill (fire-and-forget stores) ----
    {
        long long chunk = (n4 + nblk - 1) / nblk;
        long long zb = (long long)bid * chunk;
        long long ze = zb + chunk; if (ze > n4) ze = n4;
        float4 z = {0.f, 0.f, 0.f, 0.f};
        for (long long i = zb + tid; i < ze; i += 256) out4[i] = z;
    }
    // ---- decode lower-triangular tile (ti >= tj) ----
    int ti = (int)((sqrtf(8.0f * (float)bid + 1.0f) - 1.0f) * 0.5f);
    while ((ti + 1) * (ti + 2) / 2 <= bid) ++ti;
    while (ti * (ti + 1) / 2 > bid) --ti;
    int tj = bid - ti * (ti + 1) / 2;
    int r0 = ti * 64, c0 = tj * 64;
    int w = tid >> 6, l = tid & 63;
    const int kch = D >> 3;          // k-chunks of 8 per row-panel
    const bf16x8* gx = (const bf16x8*)xb;   // one bf16x8 unit = 16B
    f32x4 acc[4][4] = {};
    int kbase = w * (D >> 2);
    int ksteps = D >> 7;             // (D/4) / 32
    int l15 = l & 15, lhi = l >> 4;
    for (int ks = 0; ks < ksteps; ++ks) {
        int kc = ((kbase + ks * 32) >> 3) + lhi;   // this lane-group's 8-chunk
        bf16x8 a[4], b[4];
#pragma unroll
        for (int i = 0; i < 4; ++i)
            a[i] = gx[(((long long)((r0 >> 4) + i) * kch + kc) << 4) + l15];
#pragma unroll
        for (int j = 0; j < 4; ++j)
            b[j] = gx[(((long long)((c0 >> 4) + j) * kch + kc) << 4) + l15];
#pragma unroll
        for (int i = 0; i < 4; ++i)
#pragma unroll
            for (int j = 0; j < 4; ++j)
                acc[i][j] = __builtin_amdgcn_mfma_f32_16x16x32_bf16(a[i], b[j], acc[i][j], 0, 0, 0);
    }
    // ---- parallel cross-wave reduction: each wave writes its own region ----
    int crow = lhi * 4;
    int ccol = l15;
#pragma unroll
    for (int i = 0; i < 4; ++i)
#pragma unroll
        for (int j = 0; j < 4; ++j)
#pragma unroll
            for (int r = 0; r < 4; ++r)
                red[w][i * 16 + crow + r][j * 16 + ccol] = acc[i][j][r];
    __syncthreads();
    // ---- threshold scan (strict lower triangle only) ----
    unsigned int hit = 0;
    for (int s = tid; s < 64 * 64; s += 256) {
        int rr = s >> 6, cc = s & 63;
        int t = r0 + rr, jj = c0 + cc;
        if (t < B && jj < B && t > jj) {
            float v = red[0][rr][cc] + red[1][rr][cc] + red[2][rr][cc] + red[3][rr][cc];
            if (v >= CHECK_THRESH * pn[t] * pn[jj]) hit = 1;
        }
    }
    if (hit) atomicOr(flag, 1u);
}

// ------------- fp32 tri-check (ragged-shape fallback path) -------------
__global__ __launch_bounds__(256) void k_tricheck(const float* __restrict__ padrao,
                                                  const float* __restrict__ pn,
                                                  int B, int D,
                                                  unsigned int* __restrict__ flag) {
    __shared__ float As[64][65];
    __shared__ float Bs[64][65];
    int bid = blockIdx.x;
    int ti = (int)((sqrtf(8.0f * (float)bid + 1.0f) - 1.0f) * 0.5f);
    while ((ti + 1) * (ti + 2) / 2 <= bid) ++ti;
    while (ti * (ti + 1) / 2 > bid) --ti;
    int tj = bid - ti * (ti + 1) / 2;
    int r0 = ti * 64, c0 = tj * 64;
    int tid = threadIdx.x;
    int ty = tid >> 4, tx = tid & 15;
    float acc[4][4] = {};
    for (int k0 = 0; k0 < D; k0 += 64) {
        for (int s = tid; s < 64 * 64; s += 256) {
            int rr = s >> 6, cc = s & 63;
            int gc = k0 + cc;
            int gr = r0 + rr;
            As[rr][cc] = (gr < B && gc < D) ? padrao[(long long)gr * D + gc] : 0.0f;
            gr = c0 + rr;
            Bs[rr][cc] = (gr < B && gc < D) ? padrao[(long long)gr * D + gc] : 0.0f;
        }
        __syncthreads();
        for (int kk = 0; kk < 64; ++kk) {
            float a[4], b[4];
#pragma unroll
            for (int i = 0; i < 4; ++i) a[i] = As[ty * 4 + i][kk];
#pragma unroll
            for (int j = 0; j < 4; ++j) b[j] = Bs[tx * 4 + j][kk];
#pragma unroll
            for (int i = 0; i < 4; ++i)
#pragma unroll
                for (int j = 0; j < 4; ++j) acc[i][j] += a[i] * b[j];
        }
        __syncthreads();
    }
    unsigned int hit = 0;
    for (int i = 0; i < 4; ++i)
        for (int j = 0; j < 4; ++j) {
            int t = r0 + ty * 4 + i, jj = c0 + tx * 4 + j;
            if (t < B && jj < B && t > jj) {
                if (acc[i][j] >= CHECK_THRESH * pn[t] * pn[jj]) hit = 1;
            }
        }
    if (hit) atomicOr(flag, 1u);
}

// ---------------- zero kernels (ragged path only) ----------------
__global__ __launch_bounds__(256) void k_zero(float4* __restrict__ out, long long n4) {
    long long i = (long long)blockIdx.x * blockDim.x + threadIdx.x;
    long long stride = (long long)gridDim.x * blockDim.x;
    float4 z = {0.f, 0.f, 0.f, 0.f};
    for (; i < n4; i += stride) out[i] = z;
}
__global__ __launch_bounds__(256) void k_zero_s(float* __restrict__ out, long long n) {
    long long i = (long long)blockIdx.x * blockDim.x + threadIdx.x;
    long long stride = (long long)gridDim.x * blockDim.x;
    for (; i < n; i += stride) out[i] = 0.0f;
}

// ------- kernel 3: exact sequential fallback (runs only if flag set) -------
__global__ __launch_bounds__(1024) void k_fallback(
    const float* __restrict__ padrao, const float* __restrict__ erro,
    const float* __restrict__ protos0, const float* __restrict__ forca0,
    const int* __restrict__ n0p, const float* __restrict__ gainp,
    float* __restrict__ out, const float* __restrict__ pn_arr,
    float* __restrict__ wprotos, float* __restrict__ wforca,
    float* __restrict__ wprotn, const unsigned int* __restrict__ flag,
    int runnable, int B, int D, int P) {
    if (!runnable) return;
    if (*flag == 0) return;
    const int tid = threadIdx.x;
    const int NT = blockDim.x;
    __shared__ float rv[1024];
    __shared__ int ri[1024];
    for (long long i = tid; i < (long long)P * D; i += NT) wprotos[i] = protos0[i];
    for (int i = tid; i < P; i += NT) wforca[i] = forca0[i];
    __syncthreads();
    for (int j = tid; j < P; j += NT) {
        const float* r = wprotos + (long long)j * D;
        float s = 0.0f;
        for (int k = 0; k < D; ++k) s += r[k] * r[k];
        wprotn[j] = fmaxf(sqrtf(s), EPSV);
    }
    int n = *n0p;
    float gain = *gainp;
    __syncthreads();
    for (int t = 0; t < B; ++t) {
        const float* p = padrao + (long long)t * D;
        float pn = pn_arr[t];
        float best = -INFINITY; int bidx = 0;
        for (int j = tid; j < n; j += NT) {
            const float* r = wprotos + (long long)j * D;
            float d = 0.0f;
            for (int k = 0; k < D; ++k) d += r[k] * p[k];
            float sim = d / (wprotn[j] * pn);
            if (sim > best) { best = sim; bidx = j; }
        }
        rv[tid] = best; ri[tid] = bidx;
        __syncthreads();
        for (int off = NT >> 1; off > 0; off >>= 1) {
            if (tid < off) {
                float ov = rv[tid + off]; int oi = ri[tid + off];
                if (ov > rv[tid] || (ov == rv[tid] && oi < ri[tid])) { rv[tid] = ov; ri[tid] = oi; }
            }
            __syncthreads();
        }
        float max_sim = rv[0]; int idx = ri[0];
        __syncthreads();
        float err = erro[t];
        bool is_empty = (n == 0);
        bool do_reinf = (!is_empty) && (max_sim >= LIMIAR_SIM);
        bool do_create = is_empty || ((!do_reinf) && ((err > LIMIAR_NOVO) || (n < P)));
        if (do_create) {
            int cidx = n;
            if (n >= P) {
                float bv = INFINITY; int bi = 0;
                for (int j = tid; j < P; j += NT) {
                    float f = wforca[j];
                    if (f < bv) { bv = f; bi = j; }
                }
                rv[tid] = bv; ri[tid] = bi;
                __syncthreads();
                for (int off = NT >> 1; off > 0; off >>= 1) {
                    if (tid < off) {
                        float ov = rv[tid + off]; int oi = ri[tid + off];
                        if (ov < rv[tid] || (ov == rv[tid] && oi < ri[tid])) { rv[tid] = ov; ri[tid] = oi; }
                    }
                    __syncthreads();
                }
                cidx = ri[0];
                __syncthreads();
            }
            float* dst = wprotos + (long long)cidx * D;
            float* o = out + (long long)t * D;
            for (int k = tid; k < D; k += NT) { dst[k] = p[k]; o[k] = 0.0f; }
            if (tid == 0) { wforca[cidx] = 1.0f; wprotn[cidx] = pn; }
            if (n < P) n = n + 1;
        } else if (do_reinf) {
            float* dst = wprotos + (long long)idx * D;
            float fr_new = wforca[idx] + LR;
            float* o = out + (long long)t * D;
            float s2 = 0.0f;
            for (int k = tid; k < D; k += NT) {
                float np_ = (1.0f - LR) * dst[k] + LR * p[k];
                dst[k] = np_;
                o[k] = (np_ - p[k]) * fr_new * gain;
                s2 += np_ * np_;
            }
            rv[tid] = s2;
            __syncthreads();
            for (int off = NT >> 1; off > 0; off >>= 1) {
                if (tid < off) rv[tid] += rv[tid + off];
                __syncthreads();
            }
            if (tid == 0) { wforca[idx] = fr_new; wprotn[idx] = fmaxf(sqrtf(rv[0]), EPSV); }
        } else {
            const float* src = wprotos + (long long)idx * D;
            float fr = wforca[idx];
            float* o = out + (long long)t * D;
            for (int k = tid; k < D; k += NT) o[k] = (src[k] - p[k]) * fr * gain;
        }
        __syncthreads();
    }
}

extern "C" void kernel_launch(void* const* d_in, const int* in_sizes, int n_in,
                              void* d_out, int out_size, void* d_ws, size_t ws_size,
                              hipStream_t stream) {
    const float* padrao  = (const float*)d_in[0];
    const float* erro    = (const float*)d_in[1];
    const float* protos0 = (const float*)d_in[2];
    const float* forca0  = (const float*)d_in[3];
    const int*   n0p     = (const int*)d_in[5];
    const float* gainp   = (const float*)d_in[6];
    const int B = in_sizes[1];
    const int D = (B > 0) ? in_sizes[0] / B : 0;
    const int P = in_sizes[3];

    char* ws = (char*)d_ws;
    unsigned int* flag = (unsigned int*)ws;
    float* pn = (float*)(ws + 64);
    size_t off_xb = ((64 + (size_t)B * 4) + 63) & ~(size_t)63;
    unsigned short* xb = (unsigned short*)(ws + off_xb);
    size_t off_protos = (off_xb + (size_t)B * (size_t)D * 2 + 63) & ~(size_t)63;
    float* wprotos = (float*)(ws + off_protos);
    size_t off_forca = off_protos + (size_t)P * (size_t)D * 4;
    float* wforca = (float*)(ws + off_forca);
    size_t off_protn = off_forca + (size_t)P * 4;
    float* wprotn = (float*)(ws + off_protn);
    size_t need_total = off_protn + (size_t)P * 4;
    size_t need_fast = off_xb + (size_t)B * (size_t)D * 2;

    int runnable = (ws_size >= need_total) ? 1 : 0;
    int force_flag = (B > P) ? 1 : 0;
    int use_mfma = ((B % 64) == 0) && ((D % 128) == 0) && (ws_size >= need_fast)
                   && ((long long)out_size == (long long)B * D);

    int nT = (B + 63) / 64;
    int nblk = nT * (nT + 1) / 2;
    long long outN = (long long)out_size;

    if (use_mfma) {
        k_prep<<<B, 256, 0, stream>>>(padrao, B, D, pn, xb, 1, flag, n0p, force_flag);
        long long n4 = outN >> 2;   // outN = B*D, D%128==0 => divisible by 4
        k_trimain<<<nblk, 256, 0, stream>>>(xb, pn, B, D, flag, (float4*)d_out, n4, nblk);
    } else {
        k_prep<<<B, 256, 0, stream>>>(padrao, B, D, pn, xb, 0, flag, n0p, force_flag);
        k_tricheck<<<nblk, 256, 0, stream>>>(padrao, pn, B, D, flag);
        if ((outN & 3) == 0) {
            long long n4 = outN >> 2;
            int zb = (int)((n4 + 255) / 256); if (zb > 2048) zb = 2048; if (zb < 1) zb = 1;
            k_zero<<<zb, 256, 0, stream>>>((float4*)d_out, n4);
        } else {
            int zb = (int)((outN + 255) / 256); if (zb > 2048) zb = 2048; if (zb < 1) zb = 1;
            k_zero_s<<<zb, 256, 0, stream>>>((float*)d_out, outN);
        }
    }

    k_fallback<<<1, 1024, 0, stream>>>(padrao, erro, protos0, forca0, n0p, gainp,
                                       (float*)d_out, pn, wprotos, wforca, wprotn,
                                       flag, runnable, B, D, P);
}

// Round 7
// 31.165 us; speedup vs baseline: 7.1484x; 1.0282x over previous
//
#include <hip/hip_runtime.h>
#include <hip/hip_bf16.h>
#include <math.h>

// Engram scan. Fast path: prove on-device that every step is a "create"
// (feedback == 0) and write zeros; exact sequential fallback otherwise.
//
// Soundness (unchanged): n0==0 & B<=P => bank holds verbatim copies of
// earlier padrao rows and n<P always => every step creates unless a
// cos>=0.7 match exists among pairs (t, j<t). We flag at cos>=0.5 in bf16
// (rounding perturbs cosine <= ~0.004) -- conservative superset. Flag also
// set if n0!=0 or B>P. C-layout is the m89-verified mapping (col=lane&15,
// row=(lane>>4)*4+reg); k-permutation within lanes cancels (A and B use the
// identical lane->k map; Gram sums over k).
//
// r7 changes (r6 = 32us, k_trimain ~26us of it):
//  1. d_out zero-fill moved OUT of k_trimain into k_prep with NONTEMPORAL
//     stores: the 8MB write stream was thrashing the 4MB/XCD L2 that must
//     keep the 4MB packed xb resident -> fragment re-reads (135MB) fell out
//     of L2. k_trimain is now a pure-read kernel.
//  2. k_trimain K-split -> M-split: each wave owns a 16-row strip over the
//     full K, so no cross-wave combine: no LDS (was 66.5KB), no barrier, no
//     scan tail; threshold applied directly on acc registers. B-fragments
//     are shared by all 4 waves -> L1 broadcast; block L2 traffic unchanged.

#define LIMIAR_SIM 0.7f
#define LIMIAR_NOVO 0.3f
#define LR 0.01f
#define EPSV 1e-8f
#define CHECK_THRESH 0.5f   // conservative vs 0.7 decision threshold

typedef __attribute__((ext_vector_type(4))) float f32x4;
typedef __attribute__((ext_vector_type(8))) short bf16x8;

static __device__ inline unsigned short f2bf(float f) {
    unsigned int u = __float_as_uint(f);
    unsigned int r = (u + 0x7FFFu + ((u >> 16) & 1u)) >> 16;
    return (unsigned short)r;
}

// -- kernel 1: row norms + packed bf16 convert + nt zero-fill + flag init --
__global__ __launch_bounds__(256) void k_prep(const float* __restrict__ padrao,
                                              int B, int D, float* __restrict__ pn,
                                              unsigned short* __restrict__ xb,
                                              int do_conv,
                                              f32x4* __restrict__ out4,
                                              long long n4z, int do_zero,
                                              unsigned int* __restrict__ flag,
                                              const int* __restrict__ n0p,
                                              int force_flag) {
    __shared__ float red[4];
    int row = blockIdx.x;
    // ---- nontemporal zero-fill of this block's d_out chunk (no L2 pollution) ----
    if (do_zero) {
        long long chunk = (n4z + gridDim.x - 1) / gridDim.x;
        long long zb = (long long)row * chunk;
        long long ze = zb + chunk; if (ze > n4z) ze = n4z;
        f32x4 z = {0.f, 0.f, 0.f, 0.f};
        for (long long i = zb + threadIdx.x; i < ze; i += 256)
            __builtin_nontemporal_store(z, &out4[i]);
    }
    const float* r = padrao + (long long)row * D;
    float s = 0.0f;
    if ((D & 3) == 0) {
        for (int k = threadIdx.x * 4; k < D; k += 1024) {
            float4 v = *(const float4*)(r + k);
            s += v.x * v.x + v.y * v.y + v.z * v.z + v.w * v.w;
            if (do_conv) {
                // packed layout: elem = ((row/16 * D/8 + k/8)*16 + row%16)*8 + k%8
                long long uoff = ((((long long)(row >> 4)) * (D >> 3) + (k >> 3)) * 16
                                  + (row & 15)) * 8 + (k & 7);
                ushort4 o;
                o.x = f2bf(v.x); o.y = f2bf(v.y); o.z = f2bf(v.z); o.w = f2bf(v.w);
                *(ushort4*)(xb + uoff) = o;
            }
        }
    } else {
        for (int k = threadIdx.x; k < D; k += 256) { float v = r[k]; s += v * v; }
    }
    for (int off = 32; off > 0; off >>= 1) s += __shfl_down(s, off);
    int wid = threadIdx.x >> 6, lane = threadIdx.x & 63;
    if (lane == 0) red[wid] = s;
    __syncthreads();
    if (threadIdx.x == 0) {
        float tot = red[0] + red[1] + red[2] + red[3];
        pn[row] = fmaxf(sqrtf(tot), EPSV);
        if (row == 0) *flag = (force_flag || (*n0p != 0)) ? 1u : 0u;
    }
}

// ------- kernel 2: MFMA tri-check, M-split, no LDS, register threshold -------
// 64x64 tile/block, 4 waves; wave w owns rows [r0+16w, r0+16w+16) over full K.
// Contiguous 1KB fragment loads from the packed L2-resident buffer.
__global__ __launch_bounds__(256) void k_trimain(const unsigned short* __restrict__ xb,
                                                 const float* __restrict__ pn,
                                                 int B, int D,
                                                 unsigned int* __restrict__ flag) {
    int bid = blockIdx.x;
    // decode lower-triangular tile (ti >= tj)
    int ti = (int)((sqrtf(8.0f * (float)bid + 1.0f) - 1.0f) * 0.5f);
    while ((ti + 1) * (ti + 2) / 2 <= bid) ++ti;
    while (ti * (ti + 1) / 2 > bid) --ti;
    int tj = bid - ti * (ti + 1) / 2;
    int r0 = ti * 64, c0 = tj * 64;
    int tid = threadIdx.x;
    int w = tid >> 6, l = tid & 63;
    int l15 = l & 15, lhi = l >> 4;
    const int kch = D >> 3;                 // 8-elem k-chunks per row-panel
    const bf16x8* gx = (const bf16x8*)xb;   // one unit = 16B
    long long rpan = (long long)((r0 >> 4) + w) * kch;
    long long cpan0 = (long long)(c0 >> 4) * kch;
    f32x4 acc[4] = {};
    int ksteps = D >> 5;                    // K=32 per MFMA step
    for (int ks = 0; ks < ksteps; ++ks) {
        int kc = (ks << 2) + lhi;           // this lane-group's 8-chunk
        bf16x8 a = gx[((rpan + kc) << 4) + l15];
        bf16x8 b[4];
#pragma unroll
        for (int j = 0; j < 4; ++j)
            b[j] = gx[((cpan0 + (long long)j * kch + kc) << 4) + l15];
#pragma unroll
        for (int j = 0; j < 4; ++j)
            acc[j] = __builtin_amdgcn_mfma_f32_16x16x32_bf16(a, b[j], acc[j], 0, 0, 0);
    }
    // threshold directly on registers; C layout (m89): col=l&15, row=lhi*4+r
    int trow = r0 + w * 16 + lhi * 4;
    float pnr[4];
#pragma unroll
    for (int r = 0; r < 4; ++r) {
        int t = trow + r;
        pnr[r] = (t < B) ? pn[t] : 1.0f;
    }
    unsigned int hit = 0;
#pragma unroll
    for (int j = 0; j < 4; ++j) {
        int jj = c0 + j * 16 + l15;
        float pc = (jj < B) ? pn[jj] : 1.0f;
#pragma unroll
        for (int r = 0; r < 4; ++r) {
            int t = trow + r;
            if (t < B && jj < B && t > jj && acc[j][r] >= CHECK_THRESH * pnr[r] * pc)
                hit = 1;
        }
    }
    if (hit) atomicOr(flag, 1u);
}

// ------------- fp32 tri-check (ragged-shape fallback path) -------------
__global__ __launch_bounds__(256) void k_tricheck(const float* __restrict__ padrao,
                                                  const float* __restrict__ pn,
                                                  int B, int D,
                                                  unsigned int* __restrict__ flag) {
    __shared__ float As[64][65];
    __shared__ float Bs[64][65];
    int bid = blockIdx.x;
    int ti = (int)((sqrtf(8.0f * (float)bid + 1.0f) - 1.0f) * 0.5f);
    while ((ti + 1) * (ti + 2) / 2 <= bid) ++ti;
    while (ti * (ti + 1) / 2 > bid) --ti;
    int tj = bid - ti * (ti + 1) / 2;
    int r0 = ti * 64, c0 = tj * 64;
    int tid = threadIdx.x;
    int ty = tid >> 4, tx = tid & 15;
    float acc[4][4] = {};
    for (int k0 = 0; k0 < D; k0 += 64) {
        for (int s = tid; s < 64 * 64; s += 256) {
            int rr = s >> 6, cc = s & 63;
            int gc = k0 + cc;
            int gr = r0 + rr;
            As[rr][cc] = (gr < B && gc < D) ? padrao[(long long)gr * D + gc] : 0.0f;
            gr = c0 + rr;
            Bs[rr][cc] = (gr < B && gc < D) ? padrao[(long long)gr * D + gc] : 0.0f;
        }
        __syncthreads();
        for (int kk = 0; kk < 64; ++kk) {
            float a[4], b[4];
#pragma unroll
            for (int i = 0; i < 4; ++i) a[i] = As[ty * 4 + i][kk];
#pragma unroll
            for (int j = 0; j < 4; ++j) b[j] = Bs[tx * 4 + j][kk];
#pragma unroll
            for (int i = 0; i < 4; ++i)
#pragma unroll
                for (int j = 0; j < 4; ++j) acc[i][j] += a[i] * b[j];
        }
        __syncthreads();
    }
    unsigned int hit = 0;
    for (int i = 0; i < 4; ++i)
        for (int j = 0; j < 4; ++j) {
            int t = r0 + ty * 4 + i, jj = c0 + tx * 4 + j;
            if (t < B && jj < B && t > jj) {
                if (acc[i][j] >= CHECK_THRESH * pn[t] * pn[jj]) hit = 1;
            }
        }
    if (hit) atomicOr(flag, 1u);
}

// ---------------- zero kernels (ragged path only) ----------------
__global__ __launch_bounds__(256) void k_zero(f32x4* __restrict__ out, long long n4) {
    long long i = (long long)blockIdx.x * blockDim.x + threadIdx.x;
    long long stride = (long long)gridDim.x * blockDim.x;
    f32x4 z = {0.f, 0.f, 0.f, 0.f};
    for (; i < n4; i += stride) out[i] = z;
}
__global__ __launch_bounds__(256) void k_zero_s(float* __restrict__ out, long long n) {
    long long i = (long long)blockIdx.x * blockDim.x + threadIdx.x;
    long long stride = (long long)gridDim.x * blockDim.x;
    for (; i < n; i += stride) out[i] = 0.0f;
}

// ------- kernel 3: exact sequential fallback (runs only if flag set) -------
__global__ __launch_bounds__(1024) void k_fallback(
    const float* __restrict__ padrao, const float* __restrict__ erro,
    const float* __restrict__ protos0, const float* __restrict__ forca0,
    const int* __restrict__ n0p, const float* __restrict__ gainp,
    float* __restrict__ out, const float* __restrict__ pn_arr,
    float* __restrict__ wprotos, float* __restrict__ wforca,
    float* __restrict__ wprotn, const unsigned int* __restrict__ flag,
    int runnable, int B, int D, int P) {
    if (!runnable) return;
    if (*flag == 0) return;
    const int tid = threadIdx.x;
    const int NT = blockDim.x;
    __shared__ float rv[1024];
    __shared__ int ri[1024];
    for (long long i = tid; i < (long long)P * D; i += NT) wprotos[i] = protos0[i];
    for (int i = tid; i < P; i += NT) wforca[i] = forca0[i];
    __syncthreads();
    for (int j = tid; j < P; j += NT) {
        const float* r = wprotos + (long long)j * D;
        float s = 0.0f;
        for (int k = 0; k < D; ++k) s += r[k] * r[k];
        wprotn[j] = fmaxf(sqrtf(s), EPSV);
    }
    int n = *n0p;
    float gain = *gainp;
    __syncthreads();
    for (int t = 0; t < B; ++t) {
        const float* p = padrao + (long long)t * D;
        float pn = pn_arr[t];
        float best = -INFINITY; int bidx = 0;
        for (int j = tid; j < n; j += NT) {
            const float* r = wprotos + (long long)j * D;
            float d = 0.0f;
            for (int k = 0; k < D; ++k) d += r[k] * p[k];
            float sim = d / (wprotn[j] * pn);
            if (sim > best) { best = sim; bidx = j; }
        }
        rv[tid] = best; ri[tid] = bidx;
        __syncthreads();
        for (int off = NT >> 1; off > 0; off >>= 1) {
            if (tid < off) {
                float ov = rv[tid + off]; int oi = ri[tid + off];
                if (ov > rv[tid] || (ov == rv[tid] && oi < ri[tid])) { rv[tid] = ov; ri[tid] = oi; }
            }
            __syncthreads();
        }
        float max_sim = rv[0]; int idx = ri[0];
        __syncthreads();
        float err = erro[t];
        bool is_empty = (n == 0);
        bool do_reinf = (!is_empty) && (max_sim >= LIMIAR_SIM);
        bool do_create = is_empty || ((!do_reinf) && ((err > LIMIAR_NOVO) || (n < P)));
        if (do_create) {
            int cidx = n;
            if (n >= P) {
                float bv = INFINITY; int bi = 0;
                for (int j = tid; j < P; j += NT) {
                    float f = wforca[j];
                    if (f < bv) { bv = f; bi = j; }
                }
                rv[tid] = bv; ri[tid] = bi;
                __syncthreads();
                for (int off = NT >> 1; off > 0; off >>= 1) {
                    if (tid < off) {
                        float ov = rv[tid + off]; int oi = ri[tid + off];
                        if (ov < rv[tid] || (ov == rv[tid] && oi < ri[tid])) { rv[tid] = ov; ri[tid] = oi; }
                    }
                    __syncthreads();
                }
                cidx = ri[0];
                __syncthreads();
            }
            float* dst = wprotos + (long long)cidx * D;
            float* o = out + (long long)t * D;
            for (int k = tid; k < D; k += NT) { dst[k] = p[k]; o[k] = 0.0f; }
            if (tid == 0) { wforca[cidx] = 1.0f; wprotn[cidx] = pn; }
            if (n < P) n = n + 1;
        } else if (do_reinf) {
            float* dst = wprotos + (long long)idx * D;
            float fr_new = wforca[idx] + LR;
            float* o = out + (long long)t * D;
            float s2 = 0.0f;
            for (int k = tid; k < D; k += NT) {
                float np_ = (1.0f - LR) * dst[k] + LR * p[k];
                dst[k] = np_;
                o[k] = (np_ - p[k]) * fr_new * gain;
                s2 += np_ * np_;
            }
            rv[tid] = s2;
            __syncthreads();
            for (int off = NT >> 1; off > 0; off >>= 1) {
                if (tid < off) rv[tid] += rv[tid + off];
                __syncthreads();
            }
            if (tid == 0) { wforca[idx] = fr_new; wprotn[idx] = fmaxf(sqrtf(rv[0]), EPSV); }
        } else {
            const float* src = wprotos + (long long)idx * D;
            float fr = wforca[idx];
            float* o = out + (long long)t * D;
            for (int k = tid; k < D; k += NT) o[k] = (src[k] - p[k]) * fr * gain;
        }
        __syncthreads();
    }
}

extern "C" void kernel_launch(void* const* d_in, const int* in_sizes, int n_in,
                              void* d_out, int out_size, void* d_ws, size_t ws_size,
                              hipStream_t stream) {
    const float* padrao  = (const float*)d_in[0];
    const float* erro    = (const float*)d_in[1];
    const float* protos0 = (const float*)d_in[2];
    const float* forca0  = (const float*)d_in[3];
    const int*   n0p     = (const int*)d_in[5];
    const float* gainp   = (const float*)d_in[6];
    const int B = in_sizes[1];
    const int D = (B > 0) ? in_sizes[0] / B : 0;
    const int P = in_sizes[3];

    char* ws = (char*)d_ws;
    unsigned int* flag = (unsigned int*)ws;
    float* pn = (float*)(ws + 64);
    size_t off_xb = ((64 + (size_t)B * 4) + 63) & ~(size_t)63;
    unsigned short* xb = (unsigned short*)(ws + off_xb);
    size_t off_protos = (off_xb + (size_t)B * (size_t)D * 2 + 63) & ~(size_t)63;
    float* wprotos = (float*)(ws + off_protos);
    size_t off_forca = off_protos + (size_t)P * (size_t)D * 4;
    float* wforca = (float*)(ws + off_forca);
    size_t off_protn = off_forca + (size_t)P * 4;
    float* wprotn = (float*)(ws + off_protn);
    size_t need_total = off_protn + (size_t)P * 4;
    size_t need_fast = off_xb + (size_t)B * (size_t)D * 2;

    int runnable = (ws_size >= need_total) ? 1 : 0;
    int force_flag = (B > P) ? 1 : 0;
    int use_mfma = ((B % 64) == 0) && ((D % 128) == 0) && (ws_size >= need_fast)
                   && ((long long)out_size == (long long)B * D);

    int nT = (B + 63) / 64;
    int nblk = nT * (nT + 1) / 2;
    long long outN = (long long)out_size;

    if (use_mfma) {
        long long n4 = outN >> 2;   // outN = B*D, D%128==0 => divisible by 4
        k_prep<<<B, 256, 0, stream>>>(padrao, B, D, pn, xb, 1,
                                      (f32x4*)d_out, n4, 1, flag, n0p, force_flag);
        k_trimain<<<nblk, 256, 0, stream>>>(xb, pn, B, D, flag);
    } else {
        k_prep<<<B, 256, 0, stream>>>(padrao, B, D, pn, xb, 0,
                                      (f32x4*)d_out, 0, 0, flag, n0p, force_flag);
        k_tricheck<<<nblk, 256, 0, stream>>>(padrao, pn, B, D, flag);
        if ((outN & 3) == 0) {
            long long n4 = outN >> 2;
            int zb = (int)((n4 + 255) / 256); if (zb > 2048) zb = 2048; if (zb < 1) zb = 1;
            k_zero<<<zb, 256, 0, stream>>>((f32x4*)d_out, n4);
        } else {
            int zb = (int)((outN + 255) / 256); if (zb > 2048) zb = 2048; if (zb < 1) zb = 1;
            k_zero_s<<<zb, 256, 0, stream>>>((float*)d_out, outN);
        }
    }

    k_fallback<<<1, 1024, 0, stream>>>(padrao, erro, protos0, forca0, n0p, gainp,
                                       (float*)d_out, pn, wprotos, wforca, wprotn,
                                       flag, runnable, B, D, P);
}